// Round 4
// baseline (115.079 us; speedup 1.0000x reference)
//
#include <hip/hip_runtime.h>

// Fused masked 3x3 conv x2 (MinkowskiConv stride-1 equivalent), fp32:
//   m   = float(mask)
//   h   = relu((conv3x3(x*m, w1) + b1) * m)
//   out = (conv3x3(h, w2) + b2) * m
// LDS-tiled, 2-pixel halo. Mask folded into h's sign (enc = m ? h : -1,
// h >= 0 by ReLU) -> no staged mask array; conv1 re-reads its 2 center mask
// values from global (L1/L2-hot). All LDS tap traffic is 8B-aligned float2
// (2-way bank access = conflict-free); conv1 and conv2 both process column
// PAIRS; conv2 rolls partial row-dots down the column in registers.

#define TB_W 128           // output tile width
#define TB_H 16            // output tile height
#define SX   136           // staged width:  TB_W + 8 (16B-aligned halo)
#define SY   20            // staged height: TB_H + 4
#define NV4  (SX / 4)      // 34 float4 per staged row
#define NSTG (SY * NV4)    // 680
#define HX   130           // h region width  (TB_W + 2)
#define HY   18            // h region height (TB_H + 2)
#define HP   (HX / 2)      // 65 h-pairs per row
#define NH2  (HY * HP)     // 1170
#define SHX  132           // s_h padded width (keeps rows 8B-aligned)

__global__ __launch_bounds__(256) void fused_mconv2(
    const float* __restrict__ x, const int* __restrict__ mask,
    const float* __restrict__ w1p, const float* __restrict__ b1p,
    const float* __restrict__ w2p, const float* __restrict__ b2p,
    float* __restrict__ out, int H, int W)
{
    __shared__ __align__(16) float s_xm[SY][SX];   // x*m over halo-2 region
    __shared__ __align__(16) float s_h [HY][SHX];  // enc(h,m), col = h col

    const int tid  = threadIdx.y * 64 + threadIdx.x;     // block (64,4)
    const int c0   = blockIdx.x * TB_W;
    const int row0 = blockIdx.y * TB_H;
    const size_t plane = (size_t)H * W;
    const float* xb = x    + (size_t)blockIdx.z * plane;
    const int*   mb = mask + (size_t)blockIdx.z * plane;
    float*       ob = out  + (size_t)blockIdx.z * plane;

    float W1[9], W2[9];
    #pragma unroll
    for (int i = 0; i < 9; ++i) { W1[i] = w1p[i]; W2[i] = w2p[i]; }
    const float B1 = b1p[0], B2 = b2p[0];

    // ---- stage x*m (float4/int4 vector loads), origin (row0-2, c0-4) ----
    for (int idx = tid; idx < NSTG; idx += 256) {
        const int row  = idx / NV4;
        const int col4 = idx - row * NV4;
        const int r = row0 - 2 + row;
        const int c = c0 - 4 + (col4 << 2);
        float4 xm = make_float4(0.f, 0.f, 0.f, 0.f);
        if (r >= 0 && r < H && c >= 0 && c < W) {   // c%4==0, W%4==0 -> all-or-nothing
            const size_t g = (size_t)r * W + c;
            const float4 xv = *reinterpret_cast<const float4*>(xb + g);
            const int4   mi = *reinterpret_cast<const int4*>(mb + g);
            xm.x = mi.x ? xv.x : 0.f;
            xm.y = mi.y ? xv.y : 0.f;
            xm.z = mi.z ? xv.z : 0.f;
            xm.w = mi.w ? xv.w : 0.f;
        }
        *reinterpret_cast<float4*>(&s_xm[row][col4 << 2]) = xm;
    }
    __syncthreads();

    // ---- conv1 (pairs): enc = m ? relu(conv(x*m)+b1) : -1 over 130x18 ----
    // h point (hrow,hc) is image (row0-1+hrow, c0-1+hc); taps are s_xm rows
    // hrow..hrow+2, cols hc+2..hc+5 for the pair (4 consecutive = 2 float2).
    for (int idx = tid; idx < NH2; idx += 256) {
        const int hrow = idx / HP;
        const int hp   = idx - hrow * HP;
        const int hc   = hp << 1;
        float acc0 = B1, acc1 = B1;
        #pragma unroll
        for (int di = 0; di < 3; ++di) {
            const float2 a = *reinterpret_cast<const float2*>(&s_xm[hrow + di][hc + 2]);
            const float2 b = *reinterpret_cast<const float2*>(&s_xm[hrow + di][hc + 4]);
            acc0 += W1[di * 3] * a.x + W1[di * 3 + 1] * a.y + W1[di * 3 + 2] * b.x;
            acc1 += W1[di * 3] * a.y + W1[di * 3 + 1] * b.x + W1[di * 3 + 2] * b.y;
        }
        // center masks straight from global (L1/L2-hot from staging)
        const int r = row0 - 1 + hrow;
        int m0 = 0, m1 = 0;
        if (r >= 0 && r < H) {
            const int* rowm = mb + (size_t)r * W;
            const int ca = c0 - 1 + hc;          // ca <= W-1 always
            if (ca >= 0)    m0 = rowm[ca];
            if (ca + 1 < W) m1 = rowm[ca + 1];   // ca+1 >= 0 always
        }
        float2 enc;
        const float h0 = acc0 > 0.f ? acc0 : 0.f;
        const float h1 = acc1 > 0.f ? acc1 : 0.f;
        enc.x = m0 ? h0 : -1.0f;
        enc.y = m1 ? h1 : -1.0f;
        *reinterpret_cast<float2*>(&s_h[hrow][hc]) = enc;
    }
    __syncthreads();

    // ---- conv2 (pairs, register rolling): out = (conv(relu(enc))+b2)*m ----
    // out(i,j) taps h rows i..i+2, cols j..j+2; center enc at h(i+1, j+1).
    {
        const int p     = tid & 63;          // column pair 0..63 -> cols 2p,2p+1
        const int strip = tid >> 6;          // 0..3 -> rows 4*strip..4*strip+3
        const int j     = p << 1;
        const int hr0   = strip << 2;
        float P0 = 0.f, Q0 = 0.f, cm0 = 0.f;
        float P1 = 0.f, Q1 = 0.f, cm1 = 0.f;
        #pragma unroll
        for (int t = 0; t < 6; ++t) {
            const int hr = hr0 + t;
            const float2 a = *reinterpret_cast<const float2*>(&s_h[hr][j]);
            const float2 b = *reinterpret_cast<const float2*>(&s_h[hr][j + 2]);
            const float r0 = a.x > 0.f ? a.x : 0.f;
            const float r1 = a.y > 0.f ? a.y : 0.f;
            const float r2 = b.x > 0.f ? b.x : 0.f;
            const float r3 = b.y > 0.f ? b.y : 0.f;
            const float d00 = W2[0] * r0 + W2[1] * r1 + W2[2] * r2;
            const float d10 = W2[3] * r0 + W2[4] * r1 + W2[5] * r2;
            const float d20 = W2[6] * r0 + W2[7] * r1 + W2[8] * r2;
            const float d01 = W2[0] * r1 + W2[1] * r2 + W2[2] * r3;
            const float d11 = W2[3] * r1 + W2[4] * r2 + W2[5] * r3;
            const float d21 = W2[6] * r1 + W2[7] * r2 + W2[8] * r3;
            if (t >= 2) {
                const int i = hr - 2;
                float2 o;
                o.x = (cm0 >= 0.f) ? (Q0 + d20 + B2) : 0.f;
                o.y = (cm1 >= 0.f) ? (Q1 + d21 + B2) : 0.f;
                *reinterpret_cast<float2*>(ob + (size_t)(row0 + i) * W + (c0 + j)) = o;
            }
            Q0 = P0 + d10; P0 = d00; cm0 = a.y;   // raw enc at h(hr, j+1)
            Q1 = P1 + d11; P1 = d01; cm1 = b.x;   // raw enc at h(hr, j+2)
        }
    }
}

extern "C" void kernel_launch(void* const* d_in, const int* in_sizes, int n_in,
                              void* d_out, int out_size, void* d_ws, size_t ws_size,
                              hipStream_t stream) {
    const float* x    = (const float*)d_in[0];
    const int*   mask = (const int*)  d_in[1];
    const float* w1   = (const float*)d_in[2];
    const float* b1   = (const float*)d_in[3];
    const float* w2   = (const float*)d_in[4];
    const float* b2   = (const float*)d_in[5];
    float*       out  = (float*)d_out;

    const int H = 2048, W = 2048;
    const int B = in_sizes[0] / (H * W);

    dim3 block(64, 4, 1);
    dim3 grid(W / TB_W, H / TB_H, B);   // 16 x 128 x 8
    hipLaunchKernelGGL(fused_mconv2, grid, block, 0, stream,
                       x, mask, w1, b1, w2, b2, out, H, W);
}

// Round 5
// 104.389 us; speedup vs baseline: 1.1024x; 1.1024x over previous
//
#include <hip/hip_runtime.h>

// Fused masked 3x3 conv x2 (MinkowskiConv stride-1 equivalent), fp32:
//   m   = float(mask)
//   h   = relu((conv3x3(x*m, w1) + b1) * m)
//   out = (conv3x3(h, w2) + b2) * m
// LDS-tiled, 2-pixel halo. Two LDS arrays only (20384 B -> 8 blocks/CU):
//   s_xm : x*m over the halo-2 region
//   s_h  : staged as mask m; conv1 overwrites each point with
//          enc = m ? relu(conv1) : -1  (h >= 0, so sign carries m to conv2)
// All LDS tap reads are consecutive-address (or parity-mixed) b32 ->
// conflict-light. conv1 rolls horizontally (3 reads/col serve an 11-col
// strip); conv2 rolls vertically on column pairs.

#define TB_W 128           // output tile width
#define TB_H 16            // output tile height
#define SX   136           // s_xm width: TB_W + 8 (16B-aligned halo)
#define SY   20            // s_xm height: TB_H + 4
#define NV4  34            // SX/4 float4 per staged row
#define NSTG (SY * NV4)    // 680
#define HY   18            // h region height (TB_H + 2)
#define SHX  132           // s_h width (h cols -1..130 at sc = hc+1)
#define NMV  (HY * 34)     // 612 mask int4 items

__global__ __launch_bounds__(256) void fused_mconv2(
    const float* __restrict__ x, const int* __restrict__ mask,
    const float* __restrict__ w1p, const float* __restrict__ b1p,
    const float* __restrict__ w2p, const float* __restrict__ b2p,
    float* __restrict__ out, int H, int W)
{
    __shared__ __align__(16) float s_xm[SY][SX];
    __shared__ __align__(16) float s_h [HY][SHX];

    const int tid  = threadIdx.y * 64 + threadIdx.x;     // block (64,4)
    const int c0   = blockIdx.x * TB_W;
    const int row0 = blockIdx.y * TB_H;
    const size_t plane = (size_t)H * W;
    const float* xb = x    + (size_t)blockIdx.z * plane;
    const int*   mb = mask + (size_t)blockIdx.z * plane;
    float*       ob = out  + (size_t)blockIdx.z * plane;

    float W1[9], W2[9];
    #pragma unroll
    for (int i = 0; i < 9; ++i) { W1[i] = w1p[i]; W2[i] = w2p[i]; }
    const float B1 = b1p[0], B2 = b2p[0];

    // ---- stage x*m (float4/int4), origin (row0-2, c0-4) ----
    for (int idx = tid; idx < NSTG; idx += 256) {
        const int row  = idx / NV4;
        const int col4 = idx - row * NV4;
        const int r = row0 - 2 + row;
        const int c = c0 - 4 + (col4 << 2);
        float4 xm = make_float4(0.f, 0.f, 0.f, 0.f);
        if (r >= 0 && r < H && c >= 0 && c < W) {   // c%4==0, W%4==0 -> all-or-nothing
            const size_t g = (size_t)r * W + c;
            const float4 xv = *reinterpret_cast<const float4*>(xb + g);
            const int4   mi = *reinterpret_cast<const int4*>(mb + g);
            xm.x = mi.x ? xv.x : 0.f;
            xm.y = mi.y ? xv.y : 0.f;
            xm.z = mi.z ? xv.z : 0.f;
            xm.w = mi.w ? xv.w : 0.f;
        }
        *reinterpret_cast<float4*>(&s_xm[row][col4 << 2]) = xm;
    }

    // ---- stage mask m into s_h: h(hr,hc) mask at s_h[hr][hc+1] ----
    // int4 at image col cA = c0-4+4k covers hc = 4k-3..4k, i.e. sc = 4k-2..4k+1
    for (int idx = tid; idx < NMV; idx += 256) {
        const int hr = idx / 34;
        const int k  = idx - hr * 34;
        const int r  = row0 - 1 + hr;
        const int cA = c0 - 4 + (k << 2);
        float m0 = 0.f, m1 = 0.f, m2 = 0.f, m3 = 0.f;
        if (r >= 0 && r < H && cA >= 0 && cA < W) {
            const int4 mi = *reinterpret_cast<const int4*>(mb + (size_t)r * W + cA);
            m0 = mi.x ? 1.f : 0.f; m1 = mi.y ? 1.f : 0.f;
            m2 = mi.z ? 1.f : 0.f; m3 = mi.w ? 1.f : 0.f;
        }
        const int sc = (k << 2) - 2;
        if (k > 0)  *reinterpret_cast<float2*>(&s_h[hr][sc])     = make_float2(m0, m1);
        if (k < 33) *reinterpret_cast<float2*>(&s_h[hr][sc + 2]) = make_float2(m2, m3);
    }
    __syncthreads();

    // ---- conv1: horizontal rolling. 216 threads = 18 rows x 12 blocks of
    // 11 cols (odd width mixes LDS bank parity). Column scalars:
    // scol_dj(c) = sum_di W1[di*3+dj] * s_xm[r+di][c];
    // h(hcol) = scol_0(hcol+2) + scol_1(hcol+3) + scol_2(hcol+4) + B1.
    if (tid < 216) {
        const int r   = tid / 12;          // h row 0..17
        const int k   = tid - r * 12;      // col block 0..11
        const int hc0 = k * 11;            // h cols hc0 .. hc0+10 (clip at 129)
        float a0, b0, b1;
        {
            const int c = hc0 + 2;
            const float x0 = s_xm[r][c], x1 = s_xm[r+1][c], x2 = s_xm[r+2][c];
            a0 = W1[0]*x0 + W1[3]*x1 + W1[6]*x2;
        }
        {
            const int c = hc0 + 3;
            const float x0 = s_xm[r][c], x1 = s_xm[r+1][c], x2 = s_xm[r+2][c];
            b0 = W1[0]*x0 + W1[3]*x1 + W1[6]*x2;
            b1 = W1[1]*x0 + W1[4]*x1 + W1[7]*x2;
        }
        #pragma unroll
        for (int s = 0; s < 11; ++s) {
            const int c = hc0 + 4 + s;               // <= 131+4 = 135 < SX
            const float x0 = s_xm[r][c], x1 = s_xm[r+1][c], x2 = s_xm[r+2][c];
            const float n0 = W1[0]*x0 + W1[3]*x1 + W1[6]*x2;
            const float n1 = W1[1]*x0 + W1[4]*x1 + W1[7]*x2;
            const float n2 = W1[2]*x0 + W1[5]*x1 + W1[8]*x2;
            const int hcol = hc0 + s;
            if (hcol <= 129) {
                const float acc = a0 + b1 + n2 + B1;
                const float m   = s_h[r][hcol + 1];  // own point only
                const float h   = acc > 0.f ? acc : 0.f;
                s_h[r][hcol + 1] = (m > 0.5f) ? h : -1.0f;
            }
            a0 = b0; b0 = n0; b1 = n1;
        }
    }
    __syncthreads();

    // ---- conv2: vertical rolling on column pairs, scalar b32 taps ----
    // out(i,j) taps h rows i..i+2 (d0 row i, d1 row i+1, d2 row i+2),
    // cols j..j+2 at sc = j+1..j+3; center enc at h(i+1, j+1).
    {
        const int p     = tid & 63;          // pair -> cols 2p, 2p+1
        const int strip = tid >> 6;          // 0..3 -> out rows 4s..4s+3
        const int j     = p << 1;
        const int hr0   = strip << 2;
        float P0 = 0.f, Q0 = 0.f, cm0 = 0.f;
        float P1 = 0.f, Q1 = 0.f, cm1 = 0.f;
        #pragma unroll
        for (int t = 0; t < 6; ++t) {
            const int hr = hr0 + t;
            const float e0 = s_h[hr][j + 1];
            const float e1 = s_h[hr][j + 2];
            const float e2 = s_h[hr][j + 3];
            const float e3 = s_h[hr][j + 4];
            const float r0 = e0 > 0.f ? e0 : 0.f;
            const float r1 = e1 > 0.f ? e1 : 0.f;
            const float r2 = e2 > 0.f ? e2 : 0.f;
            const float r3 = e3 > 0.f ? e3 : 0.f;
            const float d00 = W2[0]*r0 + W2[1]*r1 + W2[2]*r2;
            const float d10 = W2[3]*r0 + W2[4]*r1 + W2[5]*r2;
            const float d20 = W2[6]*r0 + W2[7]*r1 + W2[8]*r2;
            const float d01 = W2[0]*r1 + W2[1]*r2 + W2[2]*r3;
            const float d11 = W2[3]*r1 + W2[4]*r2 + W2[5]*r3;
            const float d21 = W2[6]*r1 + W2[7]*r2 + W2[8]*r3;
            if (t >= 2) {
                const int i = hr - 2;
                float2 o;
                o.x = (cm0 >= 0.f) ? (Q0 + d20 + B2) : 0.f;
                o.y = (cm1 >= 0.f) ? (Q1 + d21 + B2) : 0.f;
                *reinterpret_cast<float2*>(ob + (size_t)(row0 + i) * W + (c0 + j)) = o;
            }
            Q0 = P0 + d10; P0 = d00; cm0 = e1;   // enc at h(hr, j+1)
            Q1 = P1 + d11; P1 = d01; cm1 = e2;   // enc at h(hr, j+2)
        }
    }
}

extern "C" void kernel_launch(void* const* d_in, const int* in_sizes, int n_in,
                              void* d_out, int out_size, void* d_ws, size_t ws_size,
                              hipStream_t stream) {
    const float* x    = (const float*)d_in[0];
    const int*   mask = (const int*)  d_in[1];
    const float* w1   = (const float*)d_in[2];
    const float* b1   = (const float*)d_in[3];
    const float* w2   = (const float*)d_in[4];
    const float* b2   = (const float*)d_in[5];
    float*       out  = (float*)d_out;

    const int H = 2048, W = 2048;
    const int B = in_sizes[0] / (H * W);

    dim3 block(64, 4, 1);
    dim3 grid(W / TB_W, H / TB_H, B);   // 16 x 128 x 8
    hipLaunchKernelGGL(fused_mconv2, grid, block, 0, stream,
                       x, mask, w1, b1, w2, b2, out, H, W);
}

// Round 6
// 91.407 us; speedup vs baseline: 1.2590x; 1.1420x over previous
//
#include <hip/hip_runtime.h>

// Fused masked 3x3 conv x2 (MinkowskiConv stride-1 equivalent), fp32:
//   m   = float(mask);  h = relu((conv3x3(x*m,w1)+b1)*m);  out = (conv3x3(h,w2)+b2)*m
//
// PURE-REGISTER row-rolling pipeline — no LDS, no __syncthreads.
// Each lane owns 4 consecutive columns; a wave owns a 256-col band and
// sweeps 36 x-rows to emit 32 output rows. Horizontal 3-taps get their
// halo from 2 lane-shuffles per conv; band edges from predicated 8B loads
// on lanes 0/63. Vertical 3-taps roll through P/Q (conv1) and R/S (conv2)
// register pairs:  h(s-1) = u0(s-2)+u1(s-1)+u2(s),  out(s-2) likewise.
// Image boundary rows/cols are correct because masked loads return 0 and
// the rolled mask registers are 0 outside the image.

#define IMG_W 2048
#define IMG_H 2048
#define BAND  256          // columns per wave (8 bands exactly cover W)
#define RPW   32           // output rows per wave
#define ITERS (RPW + 4)    // pipeline depth 4 (2 prime conv1, 2 prime conv2)

__global__ __launch_bounds__(256) void fused_mconv2_reg(
    const float* __restrict__ x, const int* __restrict__ mask,
    const float* __restrict__ w1p, const float* __restrict__ b1p,
    const float* __restrict__ w2p, const float* __restrict__ b2p,
    float* __restrict__ out)
{
    const int lane = threadIdx.x;                          // 0..63
    const int t0   = blockIdx.y * (4 * RPW) + threadIdx.y * RPW;
    const int a    = blockIdx.x * BAND;                    // band start col
    const int col  = a + (lane << 2);                      // this lane's 4 cols
    const size_t plane = (size_t)IMG_W * IMG_H;
    const float* xb = x    + (size_t)blockIdx.z * plane;
    const int*   mb = mask + (size_t)blockIdx.z * plane;
    float*       ob = out  + (size_t)blockIdx.z * plane;

    float W1[9], W2[9];
    #pragma unroll
    for (int i = 0; i < 9; ++i) { W1[i] = w1p[i]; W2[i] = w2p[i]; }
    const float B1 = b1p[0], B2 = b2p[0];

    const bool eL = (lane == 0)  && (a > 0);
    const bool eR = (lane == 63) && (a + BAND < IMG_W);

    // rolling state
    float P[4] = {0,0,0,0}, Q[4] = {0,0,0,0};   // conv1: P=u0(s-1), Q=u0(s-2)+u1(s-1)
    float R[4] = {0,0,0,0}, S[4] = {0,0,0,0};   // conv2: R=v0(u-1), S=v0(u-2)+v1(u-1)
    float PE = 0, QE = 0, PR = 0, QR = 0;       // conv1 rolling for edge cols a-1 / a+256
    float mfp[4] = {0,0,0,0}, mfq[4] = {0,0,0,0}; // mask rows s-1, s-2
    float mfEp = 0.f, mfRp = 0.f;               // edge-col masks, row s-1

    auto step = [&](int k, bool emit) {
        const int s = t0 - 2 + k;               // x-row consumed this iter
        float4 xv = make_float4(0.f, 0.f, 0.f, 0.f);
        int4   mv = make_int4(0, 0, 0, 0);
        float exm0 = 0.f, exm1 = 0.f, mfE = 0.f;   // cols a-2, a-1
        float rxm0 = 0.f, rxm1 = 0.f, mfR = 0.f;   // cols a+256, a+257
        if (s >= 0 && s < IMG_H) {              // wave-uniform
            const size_t ro = (size_t)s * IMG_W;
            xv = *reinterpret_cast<const float4*>(xb + ro + col);
            mv = *reinterpret_cast<const int4*>(mb + ro + col);
            if (eL) {
                const float2 ex = *reinterpret_cast<const float2*>(xb + ro + (a - 2));
                const int2   em = *reinterpret_cast<const int2*>(mb + ro + (a - 2));
                exm0 = ex.x * (float)em.x;  exm1 = ex.y * (float)em.y;
                mfE  = (float)em.y;
            }
            if (eR) {
                const float2 rx = *reinterpret_cast<const float2*>(xb + ro + (a + BAND));
                const int2   rm = *reinterpret_cast<const int2*>(mb + ro + (a + BAND));
                rxm0 = rx.x * (float)rm.x;  rxm1 = rx.y * (float)rm.y;
                mfR  = (float)rm.x;
            }
        }
        float mf[4] = {(float)mv.x, (float)mv.y, (float)mv.z, (float)mv.w};
        float t_[6];                             // xm window: cols col-1 .. col+4
        t_[1] = xv.x * mf[0];  t_[2] = xv.y * mf[1];
        t_[3] = xv.z * mf[2];  t_[4] = xv.w * mf[3];
        const float upx = __shfl_up(t_[4], 1);
        const float dnx = __shfl_down(t_[1], 1);
        t_[0] = (lane == 0)  ? exm1 : upx;       // xm(col-1); 0 at image edge
        t_[5] = (lane == 63) ? rxm0 : dnx;       // xm(col+4)

        // ---- conv1 dots + vertical roll: hm row s-1 ----
        float hm[4];
        #pragma unroll
        for (int c = 0; c < 4; ++c) {
            const float u0 = W1[0]*t_[c] + W1[1]*t_[c+1] + W1[2]*t_[c+2];
            const float u1 = W1[3]*t_[c] + W1[4]*t_[c+1] + W1[5]*t_[c+2];
            const float u2 = W1[6]*t_[c] + W1[7]*t_[c+1] + W1[8]*t_[c+2];
            const float h  = Q[c] + u2 + B1;     // h(s-1, col+c) pre-mask
            hm[c] = fmaxf(h, 0.f) * mfp[c];      // relu((z)*m) = max(z,0)*m
            Q[c] = P[c] + u1;
            P[c] = u0;
        }
        // edge col a-1 (lane 0 only meaningful): taps (a-2, a-1, a)
        float hmE, hmRv;
        {
            const float u0 = W1[0]*exm0 + W1[1]*exm1 + W1[2]*t_[1];
            const float u1 = W1[3]*exm0 + W1[4]*exm1 + W1[5]*t_[1];
            const float u2 = W1[6]*exm0 + W1[7]*exm1 + W1[8]*t_[1];
            const float h  = QE + u2 + B1;
            hmE = fmaxf(h, 0.f) * mfEp;
            QE = PE + u1;  PE = u0;
        }
        // edge col a+256 (lane 63 only meaningful): taps (a+255, a+256, a+257)
        {
            const float u0 = W1[0]*t_[4] + W1[1]*rxm0 + W1[2]*rxm1;
            const float u1 = W1[3]*t_[4] + W1[4]*rxm0 + W1[5]*rxm1;
            const float u2 = W1[6]*t_[4] + W1[7]*rxm0 + W1[8]*rxm1;
            const float h  = QR + u2 + B1;
            hmRv = fmaxf(h, 0.f) * mfRp;
            QR = PR + u1;  PR = u0;
        }

        // ---- conv2 on hm row s-1 ----
        float g_[6];
        g_[1] = hm[0]; g_[2] = hm[1]; g_[3] = hm[2]; g_[4] = hm[3];
        const float uph = __shfl_up(hm[3], 1);
        const float dnh = __shfl_down(hm[0], 1);
        g_[0] = (lane == 0)  ? hmE  : uph;
        g_[5] = (lane == 63) ? hmRv : dnh;

        float v0[4], v1[4], v2[4];
        #pragma unroll
        for (int c = 0; c < 4; ++c) {
            v0[c] = W2[0]*g_[c] + W2[1]*g_[c+1] + W2[2]*g_[c+2];
            v1[c] = W2[3]*g_[c] + W2[4]*g_[c+1] + W2[5]*g_[c+2];
            v2[c] = W2[6]*g_[c] + W2[7]*g_[c+1] + W2[8]*g_[c+2];
        }
        if (emit) {                              // out row s-2
            float4 o;
            o.x = (S[0] + v2[0] + B2) * mfq[0];
            o.y = (S[1] + v2[1] + B2) * mfq[1];
            o.z = (S[2] + v2[2] + B2) * mfq[2];
            o.w = (S[3] + v2[3] + B2) * mfq[3];
            *reinterpret_cast<float4*>(ob + (size_t)(s - 2) * IMG_W + col) = o;
        }
        #pragma unroll
        for (int c = 0; c < 4; ++c) { S[c] = R[c] + v1[c]; R[c] = v0[c]; }

        // rotate masks
        #pragma unroll
        for (int c = 0; c < 4; ++c) { mfq[c] = mfp[c]; mfp[c] = mf[c]; }
        mfEp = mfE;  mfRp = mfR;
    };

    // prime the 4-deep pipeline, then stream 32 emitting iterations
    step(0, false); step(1, false); step(2, false); step(3, false);
    #pragma unroll 4
    for (int k = 4; k < ITERS; ++k) step(k, true);
}

extern "C" void kernel_launch(void* const* d_in, const int* in_sizes, int n_in,
                              void* d_out, int out_size, void* d_ws, size_t ws_size,
                              hipStream_t stream) {
    const float* x    = (const float*)d_in[0];
    const int*   mask = (const int*)  d_in[1];
    const float* w1   = (const float*)d_in[2];
    const float* b1   = (const float*)d_in[3];
    const float* w2   = (const float*)d_in[4];
    const float* b2   = (const float*)d_in[5];
    float*       out  = (float*)d_out;

    const int B = in_sizes[0] / (IMG_W * IMG_H);

    dim3 block(64, 4, 1);                       // 4 independent waves
    dim3 grid(IMG_W / BAND, IMG_H / (4 * RPW), B);   // 8 x 16 x 8 = 1024 blocks
    hipLaunchKernelGGL(fused_mconv2_reg, grid, block, 0, stream,
                       x, mask, w1, b1, w2, b2, out);
}

// Round 7
// 90.773 us; speedup vs baseline: 1.2678x; 1.0070x over previous
//
#include <hip/hip_runtime.h>

// Fused masked 3x3 conv x2 (MinkowskiConv stride-1 equivalent), fp32:
//   m = float(mask); h = relu((conv3x3(x*m,w1)+b1)*m); out = (conv3x3(h,w2)+b2)*m
//
// PURE-REGISTER row-rolling pipeline — no LDS, no __syncthreads — with
// software-pipelined (ping-pong) row loads: the global loads for row k+1
// are ISSUED before row k is computed, so VMEM latency hides under the
// ~150-VALU compute body (T14 issue-early/consume-late).
// Each lane owns 4 consecutive columns; a wave owns a 256-col band and
// sweeps 20 x-rows to emit 16 output rows. Horizontal 3-tap halos come
// from 2 lane-shuffles per conv; band edges from predicated 8B loads on
// lanes 0/63. Vertical 3-taps roll through P/Q (conv1) and R/S (conv2).
// Image boundaries fall out naturally: out-of-range rows load zeros and
// the rolled mask registers are 0 outside the image.

#define IMG_W 2048
#define IMG_H 2048
#define BAND  256          // columns per wave (8 bands exactly cover W)
#define RPW   16           // output rows per wave
#define ITERS (RPW + 4)    // 20: pipeline depth 4 (2 prime conv1, 2 conv2)

struct RowIn {
    float4 xv; int4 mv;    // this lane's 4 cols
    float2 ex; int2 em;    // left  edge: cols a-2, a-1   (lane 0)
    float2 rx; int2 rm;    // right edge: cols a+256, a+257 (lane 63)
};

__global__ __launch_bounds__(256) void fused_mconv2_reg(
    const float* __restrict__ x, const int* __restrict__ mask,
    const float* __restrict__ w1p, const float* __restrict__ b1p,
    const float* __restrict__ w2p, const float* __restrict__ b2p,
    float* __restrict__ out)
{
    const int lane = threadIdx.x;                          // 0..63
    const int t0   = blockIdx.y * (4 * RPW) + threadIdx.y * RPW;
    const int a    = blockIdx.x * BAND;                    // band start col
    const int col  = a + (lane << 2);                      // this lane's 4 cols
    const size_t plane = (size_t)IMG_W * IMG_H;
    const float* xb = x    + (size_t)blockIdx.z * plane;
    const int*   mb = mask + (size_t)blockIdx.z * plane;
    float*       ob = out  + (size_t)blockIdx.z * plane;

    float W1[9], W2[9];
    #pragma unroll
    for (int i = 0; i < 9; ++i) { W1[i] = w1p[i]; W2[i] = w2p[i]; }
    const float B1 = b1p[0], B2 = b2p[0];

    const bool eL = (lane == 0)  && (a > 0);
    const bool eR = (lane == 63) && (a + BAND < IMG_W);

    // rolling state
    float P[4] = {0,0,0,0}, Q[4] = {0,0,0,0};     // conv1 vertical roll
    float R[4] = {0,0,0,0}, S[4] = {0,0,0,0};     // conv2 vertical roll
    float PE = 0, QE = 0, PR = 0, QR = 0;         // conv1 roll, edge cols
    float mfp[4] = {0,0,0,0}, mfq[4] = {0,0,0,0}; // mask rows s-1, s-2
    float mfEp = 0.f, mfRp = 0.f;                 // edge-col masks, row s-1

    auto load_row = [&](int k, RowIn& r) {
        r.xv = make_float4(0.f, 0.f, 0.f, 0.f);
        r.mv = make_int4(0, 0, 0, 0);
        r.ex = make_float2(0.f, 0.f); r.em = make_int2(0, 0);
        r.rx = make_float2(0.f, 0.f); r.rm = make_int2(0, 0);
        const int s = t0 - 2 + k;
        if (s >= 0 && s < IMG_H) {                // wave-uniform
            const size_t ro = (size_t)s * IMG_W;
            r.xv = *reinterpret_cast<const float4*>(xb + ro + col);
            r.mv = *reinterpret_cast<const int4*>(mb + ro + col);
            if (eL) {
                r.ex = *reinterpret_cast<const float2*>(xb + ro + (a - 2));
                r.em = *reinterpret_cast<const int2*>(mb + ro + (a - 2));
            }
            if (eR) {
                r.rx = *reinterpret_cast<const float2*>(xb + ro + (a + BAND));
                r.rm = *reinterpret_cast<const int2*>(mb + ro + (a + BAND));
            }
        }
    };

    auto compute = [&](const RowIn& r, int k) {
        const int s = t0 - 2 + k;
        const float exm0 = r.ex.x * (float)r.em.x;
        const float exm1 = r.ex.y * (float)r.em.y;
        const float mfE  = (float)r.em.y;
        const float rxm0 = r.rx.x * (float)r.rm.x;
        const float rxm1 = r.rx.y * (float)r.rm.y;
        const float mfR  = (float)r.rm.x;
        float mf[4] = {(float)r.mv.x, (float)r.mv.y, (float)r.mv.z, (float)r.mv.w};
        float t_[6];                              // xm window: cols col-1..col+4
        t_[1] = r.xv.x * mf[0];  t_[2] = r.xv.y * mf[1];
        t_[3] = r.xv.z * mf[2];  t_[4] = r.xv.w * mf[3];
        const float upx = __shfl_up(t_[4], 1);
        const float dnx = __shfl_down(t_[1], 1);
        t_[0] = (lane == 0)  ? exm1 : upx;        // xm(col-1); 0 at image edge
        t_[5] = (lane == 63) ? rxm0 : dnx;        // xm(col+4)

        // ---- conv1 dots + vertical roll: hm row s-1 ----
        float hm[4];
        #pragma unroll
        for (int c = 0; c < 4; ++c) {
            const float u0 = W1[0]*t_[c] + W1[1]*t_[c+1] + W1[2]*t_[c+2];
            const float u1 = W1[3]*t_[c] + W1[4]*t_[c+1] + W1[5]*t_[c+2];
            const float u2 = W1[6]*t_[c] + W1[7]*t_[c+1] + W1[8]*t_[c+2];
            const float h  = Q[c] + u2 + B1;      // h(s-1, col+c) pre-mask
            hm[c] = fmaxf(h, 0.f) * mfp[c];
            Q[c] = P[c] + u1;
            P[c] = u0;
        }
        // edge col a-1: taps (a-2, a-1, a)
        float hmE, hmRv;
        {
            const float u0 = W1[0]*exm0 + W1[1]*exm1 + W1[2]*t_[1];
            const float u1 = W1[3]*exm0 + W1[4]*exm1 + W1[5]*t_[1];
            const float u2 = W1[6]*exm0 + W1[7]*exm1 + W1[8]*t_[1];
            const float h  = QE + u2 + B1;
            hmE = fmaxf(h, 0.f) * mfEp;
            QE = PE + u1;  PE = u0;
        }
        // edge col a+256: taps (a+255, a+256, a+257)
        {
            const float u0 = W1[0]*t_[4] + W1[1]*rxm0 + W1[2]*rxm1;
            const float u1 = W1[3]*t_[4] + W1[4]*rxm0 + W1[5]*rxm1;
            const float u2 = W1[6]*t_[4] + W1[7]*rxm0 + W1[8]*rxm1;
            const float h  = QR + u2 + B1;
            hmRv = fmaxf(h, 0.f) * mfRp;
            QR = PR + u1;  PR = u0;
        }

        // ---- conv2 on hm row s-1 ----
        float g_[6];
        g_[1] = hm[0]; g_[2] = hm[1]; g_[3] = hm[2]; g_[4] = hm[3];
        const float uph = __shfl_up(hm[3], 1);
        const float dnh = __shfl_down(hm[0], 1);
        g_[0] = (lane == 0)  ? hmE  : uph;
        g_[5] = (lane == 63) ? hmRv : dnh;

        float v0[4], v1[4], v2[4];
        #pragma unroll
        for (int c = 0; c < 4; ++c) {
            v0[c] = W2[0]*g_[c] + W2[1]*g_[c+1] + W2[2]*g_[c+2];
            v1[c] = W2[3]*g_[c] + W2[4]*g_[c+1] + W2[5]*g_[c+2];
            v2[c] = W2[6]*g_[c] + W2[7]*g_[c+1] + W2[8]*g_[c+2];
        }
        if (k >= 4) {                             // out row s-2
            float4 o;
            o.x = (S[0] + v2[0] + B2) * mfq[0];
            o.y = (S[1] + v2[1] + B2) * mfq[1];
            o.z = (S[2] + v2[2] + B2) * mfq[2];
            o.w = (S[3] + v2[3] + B2) * mfq[3];
            *reinterpret_cast<float4*>(ob + (size_t)(s - 2) * IMG_W + col) = o;
        }
        #pragma unroll
        for (int c = 0; c < 4; ++c) { S[c] = R[c] + v1[c]; R[c] = v0[c]; }
        #pragma unroll
        for (int c = 0; c < 4; ++c) { mfq[c] = mfp[c]; mfp[c] = mf[c]; }
        mfEp = mfE;  mfRp = mfR;
    };

    // software-pipelined ping-pong: loads for row k+1 issue before compute(k)
    RowIn A, Bv;
    load_row(0, A);
    #pragma unroll 1
    for (int k = 0; k < ITERS; k += 2) {
        load_row(k + 1, Bv);
        compute(A, k);
        if (k + 2 < ITERS) load_row(k + 2, A);
        compute(Bv, k + 1);
    }
}

extern "C" void kernel_launch(void* const* d_in, const int* in_sizes, int n_in,
                              void* d_out, int out_size, void* d_ws, size_t ws_size,
                              hipStream_t stream) {
    const float* x    = (const float*)d_in[0];
    const int*   mask = (const int*)  d_in[1];
    const float* w1   = (const float*)d_in[2];
    const float* b1   = (const float*)d_in[3];
    const float* w2   = (const float*)d_in[4];
    const float* b2   = (const float*)d_in[5];
    float*       out  = (float*)d_out;

    const int B = in_sizes[0] / (IMG_W * IMG_H);

    dim3 block(64, 4, 1);                            // 4 independent waves
    dim3 grid(IMG_W / BAND, IMG_H / (4 * RPW), B);   // 8 x 32 x 8 = 2048 blocks
    hipLaunchKernelGGL(fused_mconv2_reg, grid, block, 0, stream,
                       x, mask, w1, b1, w2, b2, out);
}